// Round 6
// baseline (1414.913 us; speedup 1.0000x reference)
//
#include <hip/hip_runtime.h>
#include <hip/hip_bf16.h>

#define B_ 32
#define N_ 2048
#define D_ 16
#define J_ 64
#define C_ 32

// fallback (multi-kernel) geometry
#define NCHUNK 32
#define ICHUNK 64
#define IPW    16

// fused (cooperative) geometry: 1024 blocks = 16 chunks x 64 j, 4 blocks/CU
// bid = cc*64 + j  ->  all 16 chunks of a j share bid%8 (same XCD under the
// empirical round-robin mapping; speed heuristic only, not correctness).
#define NB_F   1024
#define NCH_F  16
#define ICH_F  128          // N_/NCH_F
#define IPW_F  32           // ICH_F/4 waves
#define NSUB   16           // sub-counters for the one global barrier

typedef __attribute__((ext_vector_type(8)))  short short8;
typedef __attribute__((ext_vector_type(4)))  short s16x4;
typedef __attribute__((ext_vector_type(16))) float f32x16;
typedef __attribute__((ext_vector_type(4)))  float f32x4;
typedef __attribute__((ext_vector_type(16))) int   i32x16;
typedef __attribute__((ext_vector_type(2)))  long  longx2;

using bf16_t = __hip_bfloat16;

// ===========================================================================
// FUSED cooperative kernel.
// Sync structure (contention-engineered):
//   - ONE global barrier after u-quant (two-level: 16 sub-counters, 64
//     arrivals each in parallel, + 1 top counter -> no 1024-way RMW queue).
//   - Per-iteration sync is PER-J ONLY (16 arrivals on j's own cache line):
//     PS/PZ[j] is written/read only by j's 16 chunk-blocks; Wq/SW tiles are
//     block-private across iterations (written it0, re-read by same block).
//   All counters monotone (no reset -> no ABA), zeroed by hipMemsetAsync.
// SWAPPED OPERANDS mfma(w,u) -> acc[m=c][n=b]: col b = lane&31,
// row c = (r&3)+4*(lane>>5)+8*(r>>2). int8 dequant s = sw[i,j]*su[i,b] is
// per-lane (b=lc) and folds into logit dot and S update.
// ===========================================================================
__global__ __launch_bounds__(256, 4) void fused_kernel(
    const float* __restrict__ x,
    const float* __restrict__ Wf,
    signed char* __restrict__ Wq,
    float*       __restrict__ SW,
    signed char* __restrict__ uq,
    float*       __restrict__ su,
    float*       __restrict__ PS,
    float*       __restrict__ PZ,
    float*       __restrict__ out,
    unsigned*    __restrict__ gbar)
{
  const int tid  = threadIdx.x;
  const int bid  = blockIdx.x;
  const int w    = tid >> 6;
  const int lane = tid & 63;
  const int half = lane >> 5;
  const int lc   = lane & 31;
  const int j    = bid & 63;           // 0..63
  const int cc   = bid >> 6;           // 0..15 chunk

  unsigned* top  = gbar;               // [1]  (64B-spaced counters)
  unsigned* sub  = gbar + 16;          // [NSUB], sub[g*16]
  unsigned* jcnt = gbar + 16 + 16 * NSUB;  // [64], jcnt[j*16]

  // ---- P0: quantize u rows (one thread per (i,b) row of 16) --------------
  const int gtid = bid * 256 + tid;
  if (gtid < N_ * B_) {
    const int b = gtid & 31;
    const int i = gtid >> 5;
    const float* xp = x + ((size_t)b * N_ + i) * D_;
    float v[16];
    *(f32x4*)(v)      = *(const f32x4*)(xp);
    *(f32x4*)(v + 4)  = *(const f32x4*)(xp + 4);
    *(f32x4*)(v + 8)  = *(const f32x4*)(xp + 8);
    *(f32x4*)(v + 12) = *(const f32x4*)(xp + 12);
    float m = 0.f;
#pragma unroll
    for (int k = 0; k < 16; ++k) m = fmaxf(m, fabsf(v[k]));
    m = fmaxf(m, 1e-20f);
    float inv = 127.0f / m;
    union { longx2 l2; signed char c[16]; } pk;
#pragma unroll
    for (int k = 0; k < 16; ++k) pk.c[k] = (signed char)__float2int_rn(v[k] * inv);
    *(longx2*)(uq + (size_t)gtid * D_) = pk.l2;
    su[gtid] = m * (1.0f / 127.0f);
  }

  // ---- global barrier #1 (two-level) -------------------------------------
  __syncthreads();
  if (tid == 0) {
    __threadfence();
    unsigned old = __hip_atomic_fetch_add(&sub[(bid & (NSUB - 1)) * 16], 1u,
                                          __ATOMIC_ACQ_REL, __HIP_MEMORY_SCOPE_AGENT);
    if (old + 1u == (unsigned)(NB_F / NSUB))
      __hip_atomic_fetch_add(top, 1u, __ATOMIC_ACQ_REL, __HIP_MEMORY_SCOPE_AGENT);
    while (__hip_atomic_load(top, __ATOMIC_ACQUIRE, __HIP_MEMORY_SCOPE_AGENT) <
           (unsigned)NSUB)
      __builtin_amdgcn_s_sleep(8);
    __threadfence();
  }
  __syncthreads();

  int crow[16];
#pragma unroll
  for (int r = 0; r < 16; ++r) crow[r] = (r & 3) + 4 * half + 8 * (r >> 2);

  const int ibase    = cc * ICH_F + w * IPW_F;
  const int frag_off = lc * D_ + half * 8;

  __shared__ float S_lds[4 * 32 * 33];
  __shared__ float Z_lds[4 * 32];
  __shared__ float V_lds[32 * 33];

  float V_acc[4] = {0.f, 0.f, 0.f, 0.f};
  const i32x16 zi = {0,0,0,0,0,0,0,0,0,0,0,0,0,0,0,0};

  for (int it = 0; it < 5; ++it) {
    float S[16];
#pragma unroll
    for (int r = 0; r < 16; ++r) S[r] = 0.f;
    float zacc = 0.f;

    if (it == 0) {
      // inline W quantize + uniform-weight accumulate; 2-stage pipelined
      const size_t t0 = ((size_t)ibase * J_ + j) * (C_ * D_) + frag_off;
      f32x4 w0 = *(const f32x4*)(Wf + t0);
      f32x4 w1 = *(const f32x4*)(Wf + t0 + 4);
      long  ul = *(const long*)(uq + (size_t)ibase * (B_ * D_) + frag_off);
      float suv = su[ibase * B_ + lc];

      for (int t = 0; t < IPW_F; ++t) {
        const int i   = ibase + t;
        const int tn  = (t + 1 < IPW_F) ? t + 1 : t;
        const int in_ = ibase + tn;
        const size_t tn_off = ((size_t)in_ * J_ + j) * (C_ * D_) + frag_off;
        f32x4 w0n = *(const f32x4*)(Wf + tn_off);
        f32x4 w1n = *(const f32x4*)(Wf + tn_off + 4);
        long  uln = *(const long*)(uq + (size_t)in_ * (B_ * D_) + frag_off);
        float sun = su[in_ * B_ + lc];

        float wv[8] = {w0.x, w0.y, w0.z, w0.w, w1.x, w1.y, w1.z, w1.w};
        float m = 0.f;
#pragma unroll
        for (int k = 0; k < 8; ++k) m = fmaxf(m, fabsf(wv[k]));
        m = fmaxf(m, __shfl_xor(m, 1));
        m = fmaxf(m, __shfl_xor(m, 2));
        m = fmaxf(m, __shfl_xor(m, 4));
        m = fmaxf(m, __shfl_xor(m, 8));
        m = fmaxf(m, __shfl_xor(m, 16));
        m = fmaxf(m, __shfl_xor(m, 32));
        m = fmaxf(m, 1e-20f);
        float qs = 127.0f / m;
        union { long l; signed char c[8]; } pk;
#pragma unroll
        for (int k = 0; k < 8; ++k) pk.c[k] = (signed char)__float2int_rn(wv[k] * qs);
        const size_t tile = ((size_t)i * J_ + j) * (C_ * D_);
        *(long*)(Wq + tile + frag_off) = pk.l;
        float swv = m * (1.0f / 127.0f);
        if (lane == 0) SW[(size_t)i * J_ + j] = swv;
        float sc_ = swv * suv;

        i32x16 iacc = __builtin_amdgcn_mfma_i32_32x32x16_i8(pk.l, ul, zi, 0, 0, 0);
#pragma unroll
        for (int r = 0; r < 16; ++r) S[r] = fmaf(sc_, (float)iacc[r], S[r]);

        w0 = w0n; w1 = w1n; ul = uln; suv = sun;
      }
    } else {
      float Vreg[16];
#pragma unroll
      for (int r = 0; r < 16; ++r) Vreg[r] = V_lds[lc * 33 + crow[r]];

      // 2-stage pipelined int8 loop (Wq/SW block-private, L2-resident)
      long  wl = *(const long*)(Wq + ((size_t)ibase * J_ + j) * (C_ * D_) + frag_off);
      long  ul = *(const long*)(uq + (size_t)ibase * (B_ * D_) + frag_off);
      float sc = SW[(size_t)ibase * J_ + j] * su[ibase * B_ + lc];

      for (int t = 0; t < IPW_F; ++t) {
        const int tn  = (t + 1 < IPW_F) ? t + 1 : t;
        const int in_ = ibase + tn;
        long  wl_n = *(const long*)(Wq + ((size_t)in_ * J_ + j) * (C_ * D_) + frag_off);
        long  ul_n = *(const long*)(uq + (size_t)in_ * (B_ * D_) + frag_off);
        float sc_n = SW[(size_t)in_ * J_ + j] * su[in_ * B_ + lc];

        i32x16 iacc = __builtin_amdgcn_mfma_i32_32x32x16_i8(wl, ul, zi, 0, 0, 0);

        float af[16];
        float ph = 0.f;
#pragma unroll
        for (int r = 0; r < 16; ++r) { af[r] = (float)iacc[r]; ph = fmaf(Vreg[r], af[r], ph); }
        ph *= sc;
        ph += __shfl_xor(ph, 32);
        float e = __expf(ph);
        zacc += e;
        float es = e * sc;
#pragma unroll
        for (int r = 0; r < 16; ++r) S[r] = fmaf(es, af[r], S[r]);

        wl = wl_n; ul = ul_n; sc = sc_n;
      }
    }

    // epilogue: [c][b] -> [b][c] via padded LDS, block-sum to PS/PZ (parity)
#pragma unroll
    for (int r = 0; r < 16; ++r)
      S_lds[w * 1056 + lc * 33 + crow[r]] = S[r];
    if (!half)
      Z_lds[w * 32 + lc] = (it == 0) ? (float)IPW_F : zacc;
    __syncthreads();

    const int par = it & 1;
    float* PSp = PS + (size_t)par * (NB_F * 1024);
    float* PZp = PZ + (size_t)par * (NB_F * 32);
    const size_t pbase = (size_t)bid * 1024;
    for (int e = tid; e < 1024; e += 256) {
      int b = e >> 5, c = e & 31;
      PSp[pbase + e] = S_lds[b * 33 + c] + S_lds[1056 + b * 33 + c] +
                       S_lds[2112 + b * 33 + c] + S_lds[3168 + b * 33 + c];
    }
    if (tid < 32)
      PZp[bid * 32 + tid] =
          Z_lds[tid] + Z_lds[32 + tid] + Z_lds[64 + tid] + Z_lds[96 + tid];

    // ---- per-j barrier: PS/PZ[par] of my j complete (16 arrivals) --------
    __syncthreads();
    if (tid == 0) {
      __threadfence();
      __hip_atomic_fetch_add(&jcnt[j * 16], 1u, __ATOMIC_ACQ_REL,
                             __HIP_MEMORY_SCOPE_AGENT);
      const unsigned tgt = (unsigned)(it + 1) * NCH_F;
      while (__hip_atomic_load(&jcnt[j * 16], __ATOMIC_ACQUIRE,
                               __HIP_MEMORY_SCOPE_AGENT) < tgt)
        __builtin_amdgcn_s_sleep(4);
      __threadfence();
    }
    __syncthreads();

    // local (replicated) combine for my j: squash -> v; V accumulates in LDS
    if (it < 4 || cc == 0) {
#pragma unroll
      for (int k = 0; k < 4; ++k) {
        const int e = tid + k * 256;
        const int b = e >> 5, c = e & 31;
        float s = 0.f, z = 0.f;
#pragma unroll
        for (int q = 0; q < NCH_F; ++q) {
          s += PSp[(size_t)(q * 64 + j) * 1024 + e];
          z += PZp[(q * 64 + j) * 32 + b];
        }
        float sv = s / z + 1e-7f;
        float n = sv * sv;
        n += __shfl_xor(n, 1);
        n += __shfl_xor(n, 2);
        n += __shfl_xor(n, 4);
        n += __shfl_xor(n, 8);
        n += __shfl_xor(n, 16);
        float f = n / ((1.f + n) * sqrtf(n));
        float v = sv * f;
        if (it < 4) {
          V_acc[k] = (it == 0) ? v : (V_acc[k] + v);
          V_lds[b * 33 + c] = V_acc[k];
        } else {
          out[(size_t)(b * J_ + j) * 32 + c] = v;
        }
      }
    }
    __syncthreads();
  }
}

// ===========================================================================
// Fallback multi-kernel path (round-3 verified).
// ===========================================================================
__global__ __launch_bounds__(256) void prep_u_kernel(const float* __restrict__ x,
                                                     bf16_t* __restrict__ ut,
                                                     signed char* __restrict__ uq,
                                                     float* __restrict__ su) {
  int t = blockIdx.x * 256 + threadIdx.x;
  int b = t & 31;
  int i = t >> 5;
  const float* xp = x + (size_t)(b * N_ + i) * D_;
  float v[16];
  *(f32x4*)(v)      = *(const f32x4*)(xp);
  *(f32x4*)(v + 4)  = *(const f32x4*)(xp + 4);
  *(f32x4*)(v + 8)  = *(const f32x4*)(xp + 8);
  *(f32x4*)(v + 12) = *(const f32x4*)(xp + 12);

  float m = 0.f;
#pragma unroll
  for (int k = 0; k < 16; ++k) m = fmaxf(m, fabsf(v[k]));
  m = fmaxf(m, 1e-20f);
  float inv = 127.0f / m;
  union { longx2 l2; signed char c[16]; } pk;
#pragma unroll
  for (int k = 0; k < 16; ++k) pk.c[k] = (signed char)__float2int_rn(v[k] * inv);
  *(longx2*)(uq + (size_t)t * D_) = pk.l2;
  su[t] = m * (1.0f / 127.0f);

  union { short8 s; bf16_t h[8]; } o0, o1;
#pragma unroll
  for (int k = 0; k < 8; ++k) { o0.h[k] = __float2bfloat16(v[k]); o1.h[k] = __float2bfloat16(v[8 + k]); }
  *(short8*)(ut + (size_t)t * D_)     = o0.s;
  *(short8*)(ut + (size_t)t * D_ + 8) = o1.s;
}

__global__ __launch_bounds__(256) void prep_w_kernel(const float* __restrict__ Wf,
                                                     signed char* __restrict__ Wq,
                                                     float* __restrict__ SW) {
  const int lane = threadIdx.x & 63;
  const int wid  = (blockIdx.x * 256 + threadIdx.x) >> 6;
  const int nw   = gridDim.x * 4;
  for (int tile = wid; tile < N_ * J_; tile += nw) {
    const float* wp = Wf + (size_t)tile * (C_ * D_) + lane * 8;
    f32x4 a = *(const f32x4*)wp;
    f32x4 b = *(const f32x4*)(wp + 4);
    float wv[8] = {a.x, a.y, a.z, a.w, b.x, b.y, b.z, b.w};
    float m = 0.f;
#pragma unroll
    for (int k = 0; k < 8; ++k) m = fmaxf(m, fabsf(wv[k]));
    m = fmaxf(m, __shfl_xor(m, 1));
    m = fmaxf(m, __shfl_xor(m, 2));
    m = fmaxf(m, __shfl_xor(m, 4));
    m = fmaxf(m, __shfl_xor(m, 8));
    m = fmaxf(m, __shfl_xor(m, 16));
    m = fmaxf(m, __shfl_xor(m, 32));
    m = fmaxf(m, 1e-20f);
    float qs = 127.0f / m;
    union { long l; signed char c[8]; } pk;
#pragma unroll
    for (int k = 0; k < 8; ++k) pk.c[k] = (signed char)__float2int_rn(wv[k] * qs);
    *(long*)(Wq + (size_t)tile * (C_ * D_) + lane * 8) = pk.l;
    if (lane == 0) SW[tile] = m * (1.0f / 127.0f);
  }
}

template<int MODE>
__global__ __launch_bounds__(256) void pass_kernel(
    const float*        __restrict__ Wf,
    const signed char*  __restrict__ Wq,
    const float*        __restrict__ SW,
    const signed char*  __restrict__ uq,
    const float*        __restrict__ su,
    const bf16_t*       __restrict__ ut,
    const float*        __restrict__ V,
    float*              __restrict__ PS,
    float*              __restrict__ PZ)
{
  constexpr bool UNIFORM = (MODE == 0 || MODE == 2);
  constexpr bool INT8    = (MODE == 0 || MODE == 1);

  const int tid  = threadIdx.x;
  const int w    = tid >> 6;
  const int lane = tid & 63;
  const int half = lane >> 5;
  const int lc   = lane & 31;

  const int j  = blockIdx.x / NCHUNK;
  const int ch = blockIdx.x % NCHUNK;

  int crow[16];
#pragma unroll
  for (int r = 0; r < 16; ++r) crow[r] = (r & 3) + 4 * half + 8 * (r >> 2);

  float Vreg[16];
  if (!UNIFORM) {
#pragma unroll
    for (int r = 0; r < 16; ++r) Vreg[r] = V[(lc * J_ + j) * C_ + crow[r]];
  }

  float S[16];
#pragma unroll
  for (int r = 0; r < 16; ++r) S[r] = 0.f;
  float zacc = 0.f;

  const int ibase = ch * ICHUNK + w * IPW;
  const int frag_off = lc * D_ + half * 8;

  if constexpr (INT8) {
    const i32x16 zi = {0,0,0,0,0,0,0,0,0,0,0,0,0,0,0,0};
    long wl = *(const long*)(Wq + ((size_t)ibase * J_ + j) * (C_ * D_) + frag_off);
    long ul = *(const long*)(uq + (size_t)ibase * (B_ * D_) + frag_off);
    float sc = SW[(size_t)ibase * J_ + j] * su[ibase * B_ + lc];

    for (int t = 0; t < IPW; ++t) {
      const int tn = (t + 1 < IPW) ? t + 1 : t;
      const int in_ = ibase + tn;
      long wl_n = *(const long*)(Wq + ((size_t)in_ * J_ + j) * (C_ * D_) + frag_off);
      long ul_n = *(const long*)(uq + (size_t)in_ * (B_ * D_) + frag_off);
      float sc_n = SW[(size_t)in_ * J_ + j] * su[in_ * B_ + lc];

      i32x16 iacc = __builtin_amdgcn_mfma_i32_32x32x16_i8(wl, ul, zi, 0, 0, 0);

      if constexpr (UNIFORM) {
#pragma unroll
        for (int r = 0; r < 16; ++r) S[r] = fmaf(sc, (float)iacc[r], S[r]);
      } else {
        float af[16];
        float ph = 0.f;
#pragma unroll
        for (int r = 0; r < 16; ++r) { af[r] = (float)iacc[r]; ph = fmaf(Vreg[r], af[r], ph); }
        ph *= sc;
        ph += __shfl_xor(ph, 32);
        float e = __expf(ph);
        zacc += e;
        float es = e * sc;
#pragma unroll
        for (int r = 0; r < 16; ++r) S[r] = fmaf(es, af[r], S[r]);
      }
      wl = wl_n; ul = ul_n; sc = sc_n;
    }
  } else {
    const f32x16 zeroacc = {0,0,0,0,0,0,0,0,0,0,0,0,0,0,0,0};
    for (int t = 0; t < IPW; ++t) {
      const int i = ibase + t;
      short8 ufrag = *(const short8*)(ut + (size_t)i * (B_ * D_) + frag_off);
      const size_t tile = ((size_t)i * J_ + j) * (C_ * D_);
      const float* wp = Wf + tile + frag_off;
      f32x4 w0 = *(const f32x4*)(wp);
      f32x4 w1 = *(const f32x4*)(wp + 4);
      union { short8 v; bf16_t h[8]; } cv;
      cv.h[0] = __float2bfloat16(w0.x);
      cv.h[1] = __float2bfloat16(w0.y);
      cv.h[2] = __float2bfloat16(w0.z);
      cv.h[3] = __float2bfloat16(w0.w);
      cv.h[4] = __float2bfloat16(w1.x);
      cv.h[5] = __float2bfloat16(w1.y);
      cv.h[6] = __float2bfloat16(w1.z);
      cv.h[7] = __float2bfloat16(w1.w);
      short8 wfrag = cv.v;

      f32x16 acc = __builtin_amdgcn_mfma_f32_32x32x16_bf16(wfrag, ufrag, zeroacc, 0, 0, 0);

      if constexpr (UNIFORM) {
#pragma unroll
        for (int r = 0; r < 16; ++r) S[r] += acc[r];
      } else {
        float ph = 0.f;
#pragma unroll
        for (int r = 0; r < 16; ++r) ph = fmaf(Vreg[r], acc[r], ph);
        ph += __shfl_xor(ph, 32);
        float e = __expf(ph);
        zacc += e;
#pragma unroll
        for (int r = 0; r < 16; ++r) S[r] = fmaf(e, acc[r], S[r]);
      }
    }
  }

  __shared__ float S_lds[4 * 32 * 33];
  __shared__ float Z_lds[4 * 32];
#pragma unroll
  for (int r = 0; r < 16; ++r)
    S_lds[w * 1056 + lc * 33 + crow[r]] = S[r];
  if (!half)
    Z_lds[w * 32 + lc] = UNIFORM ? (float)IPW : zacc;
  __syncthreads();

  const size_t pbase = (size_t)blockIdx.x * 1024;
  for (int e = tid; e < 1024; e += 256) {
    int b = e >> 5, c = e & 31;
    PS[pbase + e] = S_lds[b * 33 + c] + S_lds[1056 + b * 33 + c] +
                    S_lds[2112 + b * 33 + c] + S_lds[3168 + b * 33 + c];
  }
  if (tid < 32)
    PZ[(size_t)blockIdx.x * 32 + tid] =
        Z_lds[tid] + Z_lds[32 + tid] + Z_lds[64 + tid] + Z_lds[96 + tid];
}

__global__ __launch_bounds__(256) void combine_kernel(
    const float* __restrict__ PS, const float* __restrict__ PZ,
    float* __restrict__ V, float* __restrict__ out, int first, int last)
{
  int t  = blockIdx.x * 256 + threadIdx.x;
  int c  = t & 31;
  int bj = t >> 5;
  int b  = bj >> 6;
  int j  = bj & 63;
  float s = 0.f, zz = 0.f;
#pragma unroll
  for (int ch = 0; ch < NCHUNK; ++ch) {
    s  += PS[(size_t)(j * NCHUNK + ch) * 1024 + b * 32 + c];
    zz += PZ[(j * NCHUNK + ch) * 32 + b];
  }
  float sv = s / zz + 1e-7f;
  float n = sv * sv;
  n += __shfl_xor(n, 1);
  n += __shfl_xor(n, 2);
  n += __shfl_xor(n, 4);
  n += __shfl_xor(n, 8);
  n += __shfl_xor(n, 16);
  float f = n / ((1.f + n) * sqrtf(n));
  float v = sv * f;
  float Vn = first ? v : (V[t] + v);
  V[t] = Vn;
  if (last) out[t] = v;
}

extern "C" void kernel_launch(void* const* d_in, const int* in_sizes, int n_in,
                              void* d_out, int out_size, void* d_ws, size_t ws_size,
                              hipStream_t stream)
{
  const float* x  = (const float*)d_in[0];
  const float* Wf = (const float*)d_in[1];
  float* out = (float*)d_out;
  char* ws = (char*)d_ws;

  const size_t SZ_GB = 8192;                               // barrier counters
  const size_t SZ_WQ = (size_t)N_ * J_ * C_ * D_;          // 64 MB int8 W cache
  const size_t SZ_SW = (size_t)N_ * J_ * 4;                // 512 KB W tile scales
  const size_t SZ_UQ = (size_t)N_ * B_ * D_;               // 1 MB int8 u
  const size_t SZ_SU = (size_t)N_ * B_ * 4;                // 256 KB u row scales
  const size_t SZ_UT = (size_t)N_ * B_ * D_ * 2;           // 2 MB bf16 u (fallback)
  const size_t SZ_V  = (size_t)B_ * J_ * C_ * 4;           // 256 KB (fallback)
  const size_t SZ_PS = (size_t)J_ * NCHUNK * B_ * C_ * 4;  // 8 MB (= 2x1024x4KB parity)
  const size_t SZ_PZ = (size_t)J_ * NCHUNK * B_ * 4;       // 256 KB (= 2x parity)

  const bool big = ws_size >= SZ_GB + SZ_WQ + SZ_SW + SZ_UQ + SZ_SU + SZ_UT +
                              SZ_V + SZ_PS + SZ_PZ;
  char* p = ws;
  unsigned* gbar = (unsigned*)p; p += SZ_GB;
  signed char* Wq = nullptr;
  float* SWp = nullptr;
  if (big) {
    Wq  = (signed char*)p; p += SZ_WQ;
    SWp = (float*)p;       p += SZ_SW;
  }
  signed char* uq = (signed char*)p; p += SZ_UQ;
  float* su = (float*)p;             p += SZ_SU;
  bf16_t* ut = (bf16_t*)p;           p += SZ_UT;
  float*  V  = (float*)p;            p += SZ_V;
  float*  PS = (float*)p;            p += SZ_PS;
  float*  PZ = (float*)p;

  dim3 gA(J_ * NCHUNK), blk(256), gB((B_ * J_ * C_) / 256);

  if (big) {
    // ---- fused cooperative path with two-level + per-j barriers ----
    hipMemsetAsync(gbar, 0, SZ_GB, stream);
    const float* xa = x; const float* wa = Wf;
    signed char* wqa = Wq; float* swa = SWp;
    signed char* uqa = uq; float* sua = su;
    float* psa = PS; float* pza = PZ; float* oa = out; unsigned* ga = gbar;
    void* args[] = {&xa, &wa, &wqa, &swa, &uqa, &sua, &psa, &pza, &oa, &ga};
    hipError_t e = hipLaunchCooperativeKernel((const void*)fused_kernel,
                                              dim3(NB_F), dim3(256), args, 0, stream);
    if (e == hipSuccess) return;
    (void)hipGetLastError();   // clear, fall through to multi-kernel path

    prep_u_kernel<<<dim3((N_ * B_) / 256), blk, 0, stream>>>(x, ut, uq, su);
    prep_w_kernel<<<dim3(2048), blk, 0, stream>>>(Wf, Wq, SWp);
    pass_kernel<0><<<gA, blk, 0, stream>>>(nullptr, Wq, SWp, uq, su, nullptr, nullptr, PS, PZ);
    combine_kernel<<<gB, blk, 0, stream>>>(PS, PZ, V, out, 1, 0);
    for (int it = 1; it < 5; ++it) {
      pass_kernel<1><<<gA, blk, 0, stream>>>(nullptr, Wq, SWp, uq, su, nullptr, V, PS, PZ);
      combine_kernel<<<gB, blk, 0, stream>>>(PS, PZ, V, out, 0, it == 4 ? 1 : 0);
    }
  } else {
    prep_u_kernel<<<dim3((N_ * B_) / 256), blk, 0, stream>>>(x, ut, uq, su);
    pass_kernel<2><<<gA, blk, 0, stream>>>(Wf, nullptr, nullptr, uq, su, ut, nullptr, PS, PZ);
    combine_kernel<<<gB, blk, 0, stream>>>(PS, PZ, V, out, 1, 0);
    for (int it = 1; it < 5; ++it) {
      pass_kernel<3><<<gA, blk, 0, stream>>>(Wf, nullptr, nullptr, uq, su, ut, V, PS, PZ);
      combine_kernel<<<gB, blk, 0, stream>>>(PS, PZ, V, out, 0, it == 4 ? 1 : 0);
    }
  }
}

// Round 7
// 531.801 us; speedup vs baseline: 2.6606x; 2.6606x over previous
//
#include <hip/hip_runtime.h>
#include <hip/hip_bf16.h>

#define B_ 32
#define N_ 2048
#define D_ 16
#define J_ 64
#define C_ 32

// big-path geometry: 512 blocks = 64 j x 8 chunks, 2 blocks/CU
#define NCH8 8
#define ICH8 256            // N_/NCH8
#define IPW8 64             // ICH8/4 waves

// fallback (multi-kernel) geometry
#define NCHUNK 32
#define ICHUNK 64
#define IPW    16

typedef __attribute__((ext_vector_type(8)))  short short8;
typedef __attribute__((ext_vector_type(16))) float f32x16;
typedef __attribute__((ext_vector_type(4)))  float f32x4;
typedef __attribute__((ext_vector_type(16))) int   i32x16;
typedef __attribute__((ext_vector_type(2)))  long  longx2;

using bf16_t = __hip_bfloat16;

// ---------------------------------------------------------------------------
// Prep: u (B,N,D) fp32 -> uq (N,B,D) int8 + per-row scale su[i,b];
// also ut bf16 for the fallback path.
// ---------------------------------------------------------------------------
__global__ __launch_bounds__(256) void prep_u_kernel(const float* __restrict__ x,
                                                     bf16_t* __restrict__ ut,
                                                     signed char* __restrict__ uq,
                                                     float* __restrict__ su) {
  int t = blockIdx.x * 256 + threadIdx.x;   // t = i*32 + b
  int b = t & 31;
  int i = t >> 5;
  const float* xp = x + (size_t)(b * N_ + i) * D_;
  float v[16];
  *(f32x4*)(v)      = *(const f32x4*)(xp);
  *(f32x4*)(v + 4)  = *(const f32x4*)(xp + 4);
  *(f32x4*)(v + 8)  = *(const f32x4*)(xp + 8);
  *(f32x4*)(v + 12) = *(const f32x4*)(xp + 12);

  float m = 0.f;
#pragma unroll
  for (int k = 0; k < 16; ++k) m = fmaxf(m, fabsf(v[k]));
  m = fmaxf(m, 1e-20f);
  float inv = 127.0f / m;
  union { longx2 l2; signed char c[16]; } pk;
#pragma unroll
  for (int k = 0; k < 16; ++k) pk.c[k] = (signed char)__float2int_rn(v[k] * inv);
  *(longx2*)(uq + (size_t)t * D_) = pk.l2;
  su[t] = m * (1.0f / 127.0f);

  union { short8 s; bf16_t h[8]; } o0, o1;
#pragma unroll
  for (int k = 0; k < 8; ++k) { o0.h[k] = __float2bfloat16(v[k]); o1.h[k] = __float2bfloat16(v[8 + k]); }
  *(short8*)(ut + (size_t)t * D_)     = o0.s;
  *(short8*)(ut + (size_t)t * D_ + 8) = o1.s;
}

// ---------------------------------------------------------------------------
// Big-path routing pass. One block = (j, chunk of 256 i), 4 waves, wave=64 i.
// SWAPPED OPERANDS mfma(w,u) -> acc[m=c][n=b]: col b = lane&31,
// row c = (r&3)+4*(lane>>5)+8*(r>>2). int8 dequant s = sw[i,j]*su[i,b] is
// per-lane (b=lc) and folds into the logit dot and S update.
// MODE 0 (it=0): inline W-quant (Wf fp32 -> Wq int8 + SW), uniform weights.
// MODE 1 (it=1..4): HEAD-COMBINE -- recompute v_{it-1} for my j from the
//   previous pass's PS/PZ (launch boundary = sync), accumulate V (parity
//   double-buffered; duplicate writes across same-j blocks are bit-identical
//   so benign), stash V in LDS; then the int8 logit pass.
// PS/PZ are parity double-buffered across passes (WAR across launches).
// ---------------------------------------------------------------------------
template<int MODE>
__global__ __launch_bounds__(256, 2) void pass_big_kernel(
    const float*        __restrict__ Wf,   // MODE0 in
    signed char*        __restrict__ Wq,   // MODE0 out / MODE1 in
    float*              __restrict__ SW,   // MODE0 out / MODE1 in
    const signed char*  __restrict__ uq,
    const float*        __restrict__ su,
    const float*        __restrict__ PSr,  // MODE1 in  (prev parity)
    const float*        __restrict__ PZr,  // MODE1 in
    float*              __restrict__ PSw,  // out (this parity)
    float*              __restrict__ PZw,  // out
    const float*        __restrict__ Vr,   // MODE1 in  (it>=2)
    float*              __restrict__ Vw,   // MODE1 out
    int it)
{
  const int tid  = threadIdx.x;
  const int bid  = blockIdx.x;
  const int w    = tid >> 6;
  const int lane = tid & 63;
  const int half = lane >> 5;
  const int lc   = lane & 31;          // = b
  const int j    = bid >> 3;           // 0..63
  const int ch   = bid & 7;            // 0..7

  int crow[16];
#pragma unroll
  for (int r = 0; r < 16; ++r) crow[r] = (r & 3) + 4 * half + 8 * (r >> 2);

  __shared__ float S_lds[4 * 32 * 33];
  __shared__ float Z_lds[4 * 32];
  __shared__ float V_lds[32 * 33];

  float Vreg[16];
  if constexpr (MODE == 1) {
    // ---- head combine: v_{it-1} for my j (replicated across j's 8 blocks)
#pragma unroll
    for (int k = 0; k < 4; ++k) {
      const int e = tid + k * 256;     // e = b*32 + c
      const int b = e >> 5, c = e & 31;
      float s = 0.f, z = 0.f;
#pragma unroll
      for (int cc = 0; cc < NCH8; ++cc) {
        s += PSr[(size_t)(j * NCH8 + cc) * 1024 + e];
        z += PZr[(j * NCH8 + cc) * 32 + b];
      }
      float sv = s / z + 1e-7f;
      float n = sv * sv;
      n += __shfl_xor(n, 1);
      n += __shfl_xor(n, 2);
      n += __shfl_xor(n, 4);
      n += __shfl_xor(n, 8);
      n += __shfl_xor(n, 16);
      float f = n / ((1.f + n) * sqrtf(n));
      float v = sv * f;
      float Vs = (it == 1) ? v : (Vr[((size_t)b * J_ + j) * C_ + c] + v);
      Vw[((size_t)b * J_ + j) * C_ + c] = Vs;   // bit-identical dup writes
      V_lds[b * 33 + c] = Vs;
    }
    __syncthreads();
#pragma unroll
    for (int r = 0; r < 16; ++r) Vreg[r] = V_lds[lc * 33 + crow[r]];
  }

  const int ibase    = ch * ICH8 + w * IPW8;
  const int frag_off = lc * D_ + half * 8;

  float S[16];
#pragma unroll
  for (int r = 0; r < 16; ++r) S[r] = 0.f;
  float zacc = 0.f;
  const i32x16 zi = {0,0,0,0,0,0,0,0,0,0,0,0,0,0,0,0};

  if constexpr (MODE == 0) {
    // inline W quantize + uniform-weight accumulate; 2-stage pipelined
    const size_t t0 = ((size_t)ibase * J_ + j) * (C_ * D_) + frag_off;
    f32x4 w0 = *(const f32x4*)(Wf + t0);
    f32x4 w1 = *(const f32x4*)(Wf + t0 + 4);
    long  ul = *(const long*)(uq + (size_t)ibase * (B_ * D_) + frag_off);
    float suv = su[ibase * B_ + lc];

    for (int t = 0; t < IPW8; ++t) {
      const int i   = ibase + t;
      const int tn  = (t + 1 < IPW8) ? t + 1 : t;
      const int in_ = ibase + tn;
      const size_t tn_off = ((size_t)in_ * J_ + j) * (C_ * D_) + frag_off;
      f32x4 w0n = *(const f32x4*)(Wf + tn_off);
      f32x4 w1n = *(const f32x4*)(Wf + tn_off + 4);
      long  uln = *(const long*)(uq + (size_t)in_ * (B_ * D_) + frag_off);
      float sun = su[in_ * B_ + lc];

      float wv[8] = {w0.x, w0.y, w0.z, w0.w, w1.x, w1.y, w1.z, w1.w};
      float m = 0.f;
#pragma unroll
      for (int k = 0; k < 8; ++k) m = fmaxf(m, fabsf(wv[k]));
      m = fmaxf(m, __shfl_xor(m, 1));
      m = fmaxf(m, __shfl_xor(m, 2));
      m = fmaxf(m, __shfl_xor(m, 4));
      m = fmaxf(m, __shfl_xor(m, 8));
      m = fmaxf(m, __shfl_xor(m, 16));
      m = fmaxf(m, __shfl_xor(m, 32));
      m = fmaxf(m, 1e-20f);
      float qs = 127.0f / m;
      union { long l; signed char c[8]; } pk;
#pragma unroll
      for (int k = 0; k < 8; ++k) pk.c[k] = (signed char)__float2int_rn(wv[k] * qs);
      const size_t tile = ((size_t)i * J_ + j) * (C_ * D_);
      *(long*)(Wq + tile + frag_off) = pk.l;
      float swv = m * (1.0f / 127.0f);
      if (lane == 0) SW[(size_t)i * J_ + j] = swv;
      float sc_ = swv * suv;

      i32x16 iacc = __builtin_amdgcn_mfma_i32_32x32x16_i8(pk.l, ul, zi, 0, 0, 0);
#pragma unroll
      for (int r = 0; r < 16; ++r) S[r] = fmaf(sc_, (float)iacc[r], S[r]);

      w0 = w0n; w1 = w1n; ul = uln; suv = sun;
    }
  } else {
    // 2-stage pipelined int8 loop
    long  wl = *(const long*)(Wq + ((size_t)ibase * J_ + j) * (C_ * D_) + frag_off);
    long  ul = *(const long*)(uq + (size_t)ibase * (B_ * D_) + frag_off);
    float sc = SW[(size_t)ibase * J_ + j] * su[ibase * B_ + lc];

    for (int t = 0; t < IPW8; ++t) {
      const int tn  = (t + 1 < IPW8) ? t + 1 : t;
      const int in_ = ibase + tn;
      long  wl_n = *(const long*)(Wq + ((size_t)in_ * J_ + j) * (C_ * D_) + frag_off);
      long  ul_n = *(const long*)(uq + (size_t)in_ * (B_ * D_) + frag_off);
      float sc_n = SW[(size_t)in_ * J_ + j] * su[in_ * B_ + lc];

      i32x16 iacc = __builtin_amdgcn_mfma_i32_32x32x16_i8(wl, ul, zi, 0, 0, 0);

      float af[16];
      float ph = 0.f;
#pragma unroll
      for (int r = 0; r < 16; ++r) { af[r] = (float)iacc[r]; ph = fmaf(Vreg[r], af[r], ph); }
      ph *= sc;
      ph += __shfl_xor(ph, 32);
      float e = __expf(ph);
      zacc += e;
      float es = e * sc;
#pragma unroll
      for (int r = 0; r < 16; ++r) S[r] = fmaf(es, af[r], S[r]);

      wl = wl_n; ul = ul_n; sc = sc_n;
    }
  }

  // tail: [c][b] -> [b][c] via padded LDS, coalesced PS/PZ writes
#pragma unroll
  for (int r = 0; r < 16; ++r)
    S_lds[w * 1056 + lc * 33 + crow[r]] = S[r];
  if (!half)
    Z_lds[w * 32 + lc] = (MODE == 0) ? (float)IPW8 : zacc;
  __syncthreads();

  const size_t pbase = (size_t)bid * 1024;
  for (int e = tid; e < 1024; e += 256) {
    int b = e >> 5, c = e & 31;
    PSw[pbase + e] = S_lds[b * 33 + c] + S_lds[1056 + b * 33 + c] +
                     S_lds[2112 + b * 33 + c] + S_lds[3168 + b * 33 + c];
  }
  if (tid < 32)
    PZw[bid * 32 + tid] =
        Z_lds[tid] + Z_lds[32 + tid] + Z_lds[64 + tid] + Z_lds[96 + tid];
}

// ---------------------------------------------------------------------------
// Final combine: v_4 from last pass's PS/PZ -> out.
// ---------------------------------------------------------------------------
__global__ __launch_bounds__(256) void combine_final_kernel(
    const float* __restrict__ PS, const float* __restrict__ PZ,
    float* __restrict__ out)
{
  int t  = blockIdx.x * 256 + threadIdx.x;  // ((b*J + j)*32 + c)
  int c  = t & 31;
  int bj = t >> 5;
  int b  = bj >> 6;
  int j  = bj & 63;
  float s = 0.f, z = 0.f;
#pragma unroll
  for (int cc = 0; cc < NCH8; ++cc) {
    s += PS[(size_t)(j * NCH8 + cc) * 1024 + b * 32 + c];
    z += PZ[(j * NCH8 + cc) * 32 + b];
  }
  float sv = s / z + 1e-7f;
  float n = sv * sv;
  n += __shfl_xor(n, 1);
  n += __shfl_xor(n, 2);
  n += __shfl_xor(n, 4);
  n += __shfl_xor(n, 8);
  n += __shfl_xor(n, 16);
  float f = n / ((1.f + n) * sqrtf(n));
  out[t] = sv * f;
}

// ===========================================================================
// Fallback path (small ws): fp32->bf16 in-loop, round-3 verified.
// ===========================================================================
template<int MODE>   // 2: uniform, 3: V-logits
__global__ __launch_bounds__(256) void pass_kernel(
    const float*        __restrict__ Wf,
    const bf16_t*       __restrict__ ut,
    const float*        __restrict__ V,
    float*              __restrict__ PS,
    float*              __restrict__ PZ)
{
  constexpr bool UNIFORM = (MODE == 2);

  const int tid  = threadIdx.x;
  const int w    = tid >> 6;
  const int lane = tid & 63;
  const int half = lane >> 5;
  const int lc   = lane & 31;

  const int j  = blockIdx.x / NCHUNK;
  const int ch = blockIdx.x % NCHUNK;

  int crow[16];
#pragma unroll
  for (int r = 0; r < 16; ++r) crow[r] = (r & 3) + 4 * half + 8 * (r >> 2);

  float Vreg[16];
  if (!UNIFORM) {
#pragma unroll
    for (int r = 0; r < 16; ++r) Vreg[r] = V[(lc * J_ + j) * C_ + crow[r]];
  }

  float S[16];
#pragma unroll
  for (int r = 0; r < 16; ++r) S[r] = 0.f;
  float zacc = 0.f;

  const int ibase = ch * ICHUNK + w * IPW;
  const int frag_off = lc * D_ + half * 8;

  const f32x16 zeroacc = {0,0,0,0,0,0,0,0,0,0,0,0,0,0,0,0};
  for (int t = 0; t < IPW; ++t) {
    const int i = ibase + t;
    short8 ufrag = *(const short8*)(ut + (size_t)i * (B_ * D_) + frag_off);
    const size_t tile = ((size_t)i * J_ + j) * (C_ * D_);
    const float* wp = Wf + tile + frag_off;
    f32x4 w0 = *(const f32x4*)(wp);
    f32x4 w1 = *(const f32x4*)(wp + 4);
    union { short8 v; bf16_t h[8]; } cv;
    cv.h[0] = __float2bfloat16(w0.x);
    cv.h[1] = __float2bfloat16(w0.y);
    cv.h[2] = __float2bfloat16(w0.z);
    cv.h[3] = __float2bfloat16(w0.w);
    cv.h[4] = __float2bfloat16(w1.x);
    cv.h[5] = __float2bfloat16(w1.y);
    cv.h[6] = __float2bfloat16(w1.z);
    cv.h[7] = __float2bfloat16(w1.w);
    short8 wfrag = cv.v;

    f32x16 acc = __builtin_amdgcn_mfma_f32_32x32x16_bf16(wfrag, ufrag, zeroacc, 0, 0, 0);

    if constexpr (UNIFORM) {
#pragma unroll
      for (int r = 0; r < 16; ++r) S[r] += acc[r];
    } else {
      float ph = 0.f;
#pragma unroll
      for (int r = 0; r < 16; ++r) ph = fmaf(Vreg[r], acc[r], ph);
      ph += __shfl_xor(ph, 32);
      float e = __expf(ph);
      zacc += e;
#pragma unroll
      for (int r = 0; r < 16; ++r) S[r] = fmaf(e, acc[r], S[r]);
    }
  }

  __shared__ float S_lds[4 * 32 * 33];
  __shared__ float Z_lds[4 * 32];
#pragma unroll
  for (int r = 0; r < 16; ++r)
    S_lds[w * 1056 + lc * 33 + crow[r]] = S[r];
  if (!half)
    Z_lds[w * 32 + lc] = UNIFORM ? (float)IPW : zacc;
  __syncthreads();

  const size_t pbase = (size_t)blockIdx.x * 1024;
  for (int e = tid; e < 1024; e += 256) {
    int b = e >> 5, c = e & 31;
    PS[pbase + e] = S_lds[b * 33 + c] + S_lds[1056 + b * 33 + c] +
                    S_lds[2112 + b * 33 + c] + S_lds[3168 + b * 33 + c];
  }
  if (tid < 32)
    PZ[(size_t)blockIdx.x * 32 + tid] =
        Z_lds[tid] + Z_lds[32 + tid] + Z_lds[64 + tid] + Z_lds[96 + tid];
}

__global__ __launch_bounds__(256) void combine_kernel(
    const float* __restrict__ PS, const float* __restrict__ PZ,
    float* __restrict__ V, float* __restrict__ out, int first, int last)
{
  int t  = blockIdx.x * 256 + threadIdx.x;
  int c  = t & 31;
  int bj = t >> 5;
  int b  = bj >> 6;
  int j  = bj & 63;
  float s = 0.f, zz = 0.f;
#pragma unroll
  for (int ch = 0; ch < NCHUNK; ++ch) {
    s  += PS[(size_t)(j * NCHUNK + ch) * 1024 + b * 32 + c];
    zz += PZ[(j * NCHUNK + ch) * 32 + b];
  }
  float sv = s / zz + 1e-7f;
  float n = sv * sv;
  n += __shfl_xor(n, 1);
  n += __shfl_xor(n, 2);
  n += __shfl_xor(n, 4);
  n += __shfl_xor(n, 8);
  n += __shfl_xor(n, 16);
  float f = n / ((1.f + n) * sqrtf(n));
  float v = sv * f;
  float Vn = first ? v : (V[t] + v);
  V[t] = Vn;
  if (last) out[t] = v;
}

extern "C" void kernel_launch(void* const* d_in, const int* in_sizes, int n_in,
                              void* d_out, int out_size, void* d_ws, size_t ws_size,
                              hipStream_t stream)
{
  const float* x  = (const float*)d_in[0];
  const float* Wf = (const float*)d_in[1];
  float* out = (float*)d_out;
  char* ws = (char*)d_ws;

  const size_t SZ_WQ  = (size_t)N_ * J_ * C_ * D_;          // 64 MB int8 W
  const size_t SZ_SW  = (size_t)N_ * J_ * 4;                // 512 KB
  const size_t SZ_UQ  = (size_t)N_ * B_ * D_;               // 1 MB
  const size_t SZ_SU  = (size_t)N_ * B_ * 4;                // 256 KB
  const size_t SZ_UT  = (size_t)N_ * B_ * D_ * 2;           // 2 MB (fallback)
  const size_t SZ_V   = (size_t)B_ * J_ * C_ * 4;           // 256 KB (x2 parity)
  const size_t SZ_PS8 = (size_t)J_ * NCH8 * B_ * C_ * 4;    // 2 MB  (x2 parity)
  const size_t SZ_PZ8 = (size_t)J_ * NCH8 * B_ * 4;         // 64 KB (x2 parity)
  const size_t SZ_PSF = (size_t)J_ * NCHUNK * B_ * C_ * 4;  // 8 MB  (fallback)
  const size_t SZ_PZF = (size_t)J_ * NCHUNK * B_ * 4;       // 256 KB (fallback)

  const size_t need_big = SZ_WQ + SZ_SW + SZ_UQ + SZ_SU + SZ_UT +
                          2 * SZ_V + 2 * SZ_PS8 + 2 * SZ_PZ8;
  const bool big = ws_size >= need_big;

  dim3 blk(256);

  if (big) {
    char* p = ws;
    signed char* Wq = (signed char*)p; p += SZ_WQ;
    float* SWp = (float*)p;            p += SZ_SW;
    signed char* uq = (signed char*)p; p += SZ_UQ;
    float* su = (float*)p;             p += SZ_SU;
    bf16_t* ut = (bf16_t*)p;           p += SZ_UT;
    float* V0  = (float*)p;            p += SZ_V;
    float* V1  = (float*)p;            p += SZ_V;
    float* PS0 = (float*)p;            p += SZ_PS8;
    float* PS1 = (float*)p;            p += SZ_PS8;
    float* PZ0 = (float*)p;            p += SZ_PZ8;
    float* PZ1 = (float*)p;

    prep_u_kernel<<<dim3((N_ * B_) / 256), blk, 0, stream>>>(x, ut, uq, su);

    // it0: inline W-quant + uniform weights -> PS0/PZ0
    pass_big_kernel<0><<<dim3(J_ * NCH8), blk, 0, stream>>>(
        Wf, Wq, SWp, uq, su, nullptr, nullptr, PS0, PZ0, V0, V0, 0);

    // it1..4: head-combine + int8 logit pass, parity swap each iter
    for (int it = 1; it < 5; ++it) {
      float* psw = (it & 1) ? PS1 : PS0;
      float* pzw = (it & 1) ? PZ1 : PZ0;
      const float* psr = (it & 1) ? PS0 : PS1;
      const float* pzr = (it & 1) ? PZ0 : PZ1;
      float* vw = (it & 1) ? V1 : V0;
      const float* vr = (it & 1) ? V0 : V1;
      pass_big_kernel<1><<<dim3(J_ * NCH8), blk, 0, stream>>>(
          nullptr, Wq, SWp, uq, su, psr, pzr, psw, pzw, vr, vw, it);
    }
    // it4 wrote parity 0
    combine_final_kernel<<<dim3((B_ * J_ * C_) / 256), blk, 0, stream>>>(PS0, PZ0, out);
  } else {
    char* p = ws;
    signed char* uq = (signed char*)p; p += SZ_UQ;
    float* su = (float*)p;             p += SZ_SU;
    bf16_t* ut = (bf16_t*)p;           p += SZ_UT;
    float*  V  = (float*)p;            p += SZ_V;
    float*  PS = (float*)p;            p += SZ_PSF;
    float*  PZ = (float*)p;

    dim3 gA(J_ * NCHUNK), gB((B_ * J_ * C_) / 256);
    prep_u_kernel<<<dim3((N_ * B_) / 256), blk, 0, stream>>>(x, ut, uq, su);
    pass_kernel<2><<<gA, blk, 0, stream>>>(Wf, ut, nullptr, PS, PZ);
    combine_kernel<<<gB, blk, 0, stream>>>(PS, PZ, V, out, 1, 0);
    for (int it = 1; it < 5; ++it) {
      pass_kernel<3><<<gA, blk, 0, stream>>>(Wf, ut, V, PS, PZ);
      combine_kernel<<<gB, blk, 0, stream>>>(PS, PZ, V, out, 0, it == 4 ? 1 : 0);
    }
  }
}